// Round 4
// baseline (138.015 us; speedup 1.0000x reference)
//
#include <hip/hip_runtime.h>

#define NN 4096
#define DD 128
#define MMR 2048
#define KKE 1024
#define FJS 32
#define FCOLS (NN / FJS)      // 128
#define FTILES (FCOLS / 16)   // 8

typedef __attribute__((ext_vector_type(8))) short s16x8;
typedef __attribute__((ext_vector_type(4))) float f32x4;
typedef unsigned short u16;
typedef unsigned int u32;

// ln(1e-45) in fp32
#define SMALLV (-103.61632918439092f)
// exp(2*v - 4) == exp2(v*K1 + K2)
#define K1EXP 2.8853900817779268f
#define K2EXP (-5.7707801635558537f)

static __device__ __forceinline__ u16 f2bf(float x) {
    u32 u = __float_as_uint(x);
    u32 r = (u + 0x7fffu + ((u >> 16) & 1u)) >> 16;
    return (u16)r;
}

static __device__ __forceinline__ f32x4 mfma_bf16(s16x8 a, s16x8 b, f32x4 c) {
    return __builtin_amdgcn_mfma_f32_16x16x32_bf16(a, b, c, 0, 0, 0);
}

// ---------------- prep: all conversions in one launch (linear layout) ----------------
__global__ __launch_bounds__(256) void prep_all(
    const float* __restrict__ zi, const float* __restrict__ z,
    const float* __restrict__ real, const float* __restrict__ pseudo,
    const float* __restrict__ pseudos,
    u16* __restrict__ zin_bf, u16* __restrict__ zn_bf,
    u16* __restrict__ real_bf, u16* __restrict__ pseudo_bf,
    u16* __restrict__ pseudos_bf,
    float* __restrict__ nreal, float* __restrict__ npseudo,
    float* __restrict__ npseudos)
{
    int b = blockIdx.x;
    int sub = threadIdx.x >> 6, lane = threadIdx.x & 63;
    if (b < 2048) {
        int row = b * 4 + sub;   // 0..8191
        const float* src = (row < NN) ? zi : z;
        u16* dst = (row < NN) ? zin_bf : zn_bf;
        int r = (row < NN) ? row : row - NN;
        const float* p = src + (size_t)r * DD;
        float a = p[lane], c = p[lane + 64];
        float ss = a * a + c * c;
        #pragma unroll
        for (int d = 1; d < 64; d <<= 1) ss += __shfl_xor(ss, d);
        float nrm = fmaxf(sqrtf(ss), 1e-8f);
        dst[r * DD + lane]      = f2bf(a / nrm);
        dst[r * DD + lane + 64] = f2bf(c / nrm);
    } else {
        const float* src; u16* dst; float* sq; int r;
        if (b < 3072)      { r = (b - 2048) * 4 + sub; src = real;    dst = real_bf;    sq = nreal; }
        else if (b < 3584) { r = (b - 3072) * 4 + sub; src = pseudo;  dst = pseudo_bf;  sq = npseudo; }
        else               { r = (b - 3584) * 4 + sub; src = pseudos; dst = pseudos_bf; sq = npseudos; }
        const float* p = src + (size_t)r * DD;
        float a = p[lane], c = p[lane + 64];
        float ss = a * a + c * c;
        #pragma unroll
        for (int d = 1; d < 64; d <<= 1) ss += __shfl_xor(ss, d);
        if (lane == 0) sq[r] = ss;
        dst[r * DD + lane]      = f2bf(a);
        dst[r * DD + lane + 64] = f2bf(c);
    }
}

// ---------------- feature loss: single-wave blocks, register pipeline ----------------
// No LDS, no barriers. A-frags (J-tiles) double-buffered +2 ahead; masks
// triple-buffered +3 ahead. Each wave: 16 R-rows x 128 J-cols.
__global__ __launch_bounds__(64, 2) void feat_kernel(
    const u16* __restrict__ zin, const u16* __restrict__ zn,
    const float* __restrict__ y_pse, const float* __restrict__ negw,
    const int* __restrict__ w,
    float* __restrict__ row_s, float* __restrict__ pos_part)
{
    int js = blockIdx.x % FJS;
    int rb = blockIdx.x / FJS;          // 0..255
    int lane = threadIdx.x;             // 0..63
    int lr = lane & 15, lg = lane >> 4;
    int R = rb * 16 + lr;
    const short* zin_s = (const short*)zin;
    const short* zn_s  = (const short*)zn;

    // B operand: zi rows R, held for the whole kernel
    s16x8 bfrag[4];
    #pragma unroll
    for (int kk = 0; kk < 4; ++kk)
        bfrag[kk] = *(const s16x8*)(zin_s + (size_t)R * DD + kk * 32 + lg * 8);

    const float4* yp  = (const float4*)(y_pse + (size_t)R * NN);
    const float4* npw = (const float4*)(negw  + (size_t)R * NN);
    const int4*   wp  = (const int4*)(w       + (size_t)R * NN);
    int j0base = js * FCOLS;
    int qbase = (j0base >> 2) + lg;

    s16x8 fN[2][4], fI[2][4];           // A-frags: zn (cross), zin (inter)
    float4 yv[3], nv[3];
    int4   wv[3];

    // prologue: frags for tiles 0,1; masks for tiles 0,1,2
    #pragma unroll
    for (int b = 0; b < 2; ++b) {
        int jr = j0base + b * 16 + lr;
        #pragma unroll
        for (int kk = 0; kk < 4; ++kk) {
            fN[b][kk] = *(const s16x8*)(zn_s  + (size_t)jr * DD + kk * 32 + lg * 8);
            fI[b][kk] = *(const s16x8*)(zin_s + (size_t)jr * DD + kk * 32 + lg * 8);
        }
    }
    #pragma unroll
    for (int b = 0; b < 3; ++b) {
        yv[b] = yp[qbase + b * 4];
        nv[b] = npw[qbase + b * 4];
        wv[b] = wp[qbase + b * 4];
    }

    float s0 = 0.0f, pos = 0.0f;

    #pragma unroll
    for (int t = 0; t < FTILES; ++t) {
        const int fc = t & 1;
        const int mc = t % 3;
        f32x4 accc = {0.f, 0.f, 0.f, 0.f}, acci = {0.f, 0.f, 0.f, 0.f};
        #pragma unroll
        for (int kk = 0; kk < 4; ++kk) {
            accc = mfma_bf16(fN[fc][kk], bfrag[kk], accc);   // C[J,R] = z[J]·zi[R]
            acci = mfma_bf16(fI[fc][kk], bfrag[kk], acci);   // C[J,R] = zi[J]·zi[R]
        }
        int j0 = j0base + t * 16;
        float ya[4] = {yv[mc].x, yv[mc].y, yv[mc].z, yv[mc].w};
        float na[4] = {nv[mc].x, nv[mc].y, nv[mc].z, nv[mc].w};
        int   wa[4] = {wv[mc].x, wv[mc].y, wv[mc].z, wv[mc].w};
        #pragma unroll
        for (int r = 0; r < 4; ++r) {
            int J = j0 + lg * 4 + r;
            float y = ya[r];
            bool wm = (wa[r] != 0) || (R == J);
            float cross = accc[r] * 2.0f;   // cos / TEMP
            float inter = acci[r] * 2.0f;
            if (wm && (y > 0.0f)) pos += y * cross;
            bool nm = (!wm) && (y == 0.0f);
            float nwc = fmaxf(na[r], 0.0f);
            float vc = nm ? nwc * cross : 0.0f;
            vc = (vc == 0.0f) ? SMALLV : vc;
            float vi = nm ? nwc * inter : 0.0f;
            vi = (vi == 0.0f) ? SMALLV : vi;
            s0 += exp2f(fmaf(vc, K1EXP, K2EXP)) + exp2f(fmaf(vi, K1EXP, K2EXP));
        }
        // refill consumed slots (frags +2 ahead, masks +3 ahead)
        if (t + 2 < FTILES) {
            int jr = j0base + (t + 2) * 16 + lr;
            #pragma unroll
            for (int kk = 0; kk < 4; ++kk) {
                fN[fc][kk] = *(const s16x8*)(zn_s  + (size_t)jr * DD + kk * 32 + lg * 8);
                fI[fc][kk] = *(const s16x8*)(zin_s + (size_t)jr * DD + kk * 32 + lg * 8);
            }
        }
        if (t + 3 < FTILES) {
            int q = qbase + (t + 3) * 4;
            yv[mc] = yp[q]; nv[mc] = npw[q]; wv[mc] = wp[q];
        }
    }

    // combine s0 across lg groups (lanes lr, lr+16, lr+32, lr+48 share R)
    #pragma unroll
    for (int d = 16; d < 64; d <<= 1) s0 += __shfl_xor(s0, d);
    if (lg == 0) row_s[(size_t)R * FJS + js] = s0;
    #pragma unroll
    for (int d = 1; d < 64; d <<= 1) pos += __shfl_xor(pos, d);
    if (lane == 0) pos_part[blockIdx.x] = pos;
}

// ---------------- RBF pair-sums, all four in one launch ----------------
__global__ __launch_bounds__(256) void rbf_all(
    const u16* __restrict__ real_bf, const u16* __restrict__ pseudo_bf,
    const u16* __restrict__ pseudos_bf,
    const float* __restrict__ nreal, const float* __restrict__ npseudo,
    const float* __restrict__ npseudos,
    float* __restrict__ partials)
{
    int b = blockIdx.x;
    const u16 *X, *Y; const float *nx, *ny;
    int js, cols, same, local;
    if (b < 512)       { X = real_bf;    Y = real_bf;    nx = nreal;    ny = nreal;    js = 16; cols = 256; same = 1; local = b; }
    else if (b < 768)  { X = pseudo_bf;  Y = pseudo_bf;  nx = npseudo;  ny = npseudo;  js = 16; cols = 128; same = 1; local = b - 512; }
    else if (b < 1024) { X = real_bf;    Y = pseudo_bf;  nx = nreal;    ny = npseudo;  js = 8;  cols = 256; same = 0; local = b - 768; }
    else               { X = pseudos_bf; Y = pseudos_bf; nx = npseudos; ny = npseudos; js = 8;  cols = 128; same = 1; local = b - 1024; }
    int jsx = local % js;
    int rb  = local / js;
    int wid = threadIdx.x >> 6;
    int lane = threadIdx.x & 63;
    int lr = lane & 15, lg = lane >> 4;
    int row0 = rb * 128 + wid * 32;
    const short* Xs = (const short*)X;
    const short* Ys = (const short*)Y;
    s16x8 a0[4], a1[4];
    #pragma unroll
    for (int kk = 0; kk < 4; ++kk) {
        a0[kk] = *(const s16x8*)(Xs + (size_t)(row0 + lr) * DD + kk * 32 + lg * 8);
        a1[kk] = *(const s16x8*)(Xs + (size_t)(row0 + 16 + lr) * DD + kk * 32 + lg * 8);
    }
    float nx0[4], nx1[4];
    #pragma unroll
    for (int r = 0; r < 4; ++r) {
        nx0[r] = nx[row0 + lg * 4 + r];
        nx1[r] = nx[row0 + 16 + lg * 4 + r];
    }
    float sum = 0.0f;
    int j0base = jsx * cols;
    for (int j0 = j0base; j0 < j0base + cols; j0 += 16) {
        int brow = j0 + lr;
        f32x4 c0 = {0.f, 0.f, 0.f, 0.f}, c1 = {0.f, 0.f, 0.f, 0.f};
        #pragma unroll
        for (int kk = 0; kk < 4; ++kk) {
            s16x8 bb = *(const s16x8*)(Ys + (size_t)brow * DD + kk * 32 + lg * 8);
            c0 = mfma_bf16(a0[kk], bb, c0);
            c1 = mfma_bf16(a1[kk], bb, c1);
        }
        int J = j0 + lr;
        float nyJ = ny[J];
        #pragma unroll
        for (int r = 0; r < 4; ++r) {
            int R0 = row0 + lg * 4 + r;
            float d0 = fmaxf(nx0[r] + nyJ - 2.0f * c0[r], 0.0f);
            if (!(same && (R0 == J))) sum += __expf(-d0 * 0.125f);
            int R1 = R0 + 16;
            float d1 = fmaxf(nx1[r] + nyJ - 2.0f * c1[r], 0.0f);
            if (!(same && (R1 == J))) sum += __expf(-d1 * 0.125f);
        }
    }
    #pragma unroll
    for (int d = 1; d < 64; d <<= 1) sum += __shfl_xor(sum, d);
    __shared__ float lds_s[4];
    if (lane == 0) lds_s[wid] = sum;
    __syncthreads();
    if (threadIdx.x == 0)
        partials[b] = lds_s[0] + lds_s[1] + lds_s[2] + lds_s[3];
}

// ---------------- per-row LSE finish ----------------
__global__ __launch_bounds__(256) void lse_part_kernel(
    const float* __restrict__ row_s, float* __restrict__ lse_part)
{
    int R = blockIdx.x * 256 + threadIdx.x;
    float s = 0.0f;
    #pragma unroll
    for (int k = 0; k < FJS; ++k) s += row_s[(size_t)R * FJS + k];
    float v = 4.0f + __logf(s);   // fixed-max LSE: max = 4
    #pragma unroll
    for (int d = 1; d < 64; d <<= 1) v += __shfl_xor(v, d);
    __shared__ float l[4];
    if ((threadIdx.x & 63) == 0) l[threadIdx.x >> 6] = v;
    __syncthreads();
    if (threadIdx.x == 0) lse_part[blockIdx.x] = l[0] + l[1] + l[2] + l[3];
}

// ---------------- final (1 block, deterministic) ----------------
__global__ __launch_bounds__(256) void final_kernel(
    const float* __restrict__ lse_part, const float* __restrict__ pos_part,
    const float* __restrict__ partials, float* __restrict__ out)
{
    int t = threadIdx.x;
    float lse = (t < 16) ? lse_part[t] : 0.0f;
    float pos = 0.0f;
    #pragma unroll
    for (int i = 0; i < 32; ++i) pos += pos_part[t + 256 * i];
    float xx = partials[t] + partials[t + 256];
    float yy = partials[512 + t];
    float xy = partials[768 + t];
    float pp = (t < 64) ? partials[1024 + t] : 0.0f;
    __shared__ float red[256];
    float vals[6] = {lse, pos, xx, yy, xy, pp};
    float tot[6];
    #pragma unroll
    for (int v = 0; v < 6; ++v) {
        red[t] = vals[v];
        __syncthreads();
        for (int d = 128; d > 0; d >>= 1) {
            if (t < d) red[t] += red[t + d];
            __syncthreads();
        }
        tot[v] = red[0];
        __syncthreads();
    }
    if (t == 0) {
        float feat = (tot[0] - tot[1]) / (float)NN;
        float sxx = tot[2] / ((float)NN * (NN - 1));
        float syy = tot[3] / ((float)MMR * (MMR - 1));
        float sxy = 2.0f * tot[4] / ((float)NN * MMR);
        out[0] = feat + sxx + syy - sxy + tot[5];
    }
}

extern "C" void kernel_launch(void* const* d_in, const int* in_sizes, int n_in,
                              void* d_out, int out_size, void* d_ws, size_t ws_size,
                              hipStream_t stream) {
    const float* zi      = (const float*)d_in[0];
    const float* z       = (const float*)d_in[1];
    const float* y_pse   = (const float*)d_in[2];
    const float* negw    = (const float*)d_in[3];
    const float* real    = (const float*)d_in[4];
    const float* pseudo  = (const float*)d_in[5];
    const float* pseudos = (const float*)d_in[6];
    const int*   w       = (const int*)d_in[7];
    float* out = (float*)d_out;

    char* ws = (char*)d_ws;
    u16* zin_bf     = (u16*)(ws + 0);                     // 1 MB
    u16* zn_bf      = (u16*)(ws + (1 << 20));             // 1 MB
    u16* real_bf    = (u16*)(ws + (2 << 20));             // 1 MB
    u16* pseudo_bf  = (u16*)(ws + (3 << 20));             // 512 KB
    u16* pseudos_bf = (u16*)(ws + (3 << 20) + (1 << 19)); // 256 KB
    float* nreal    = (float*)(ws + (15 << 18));          // 16 KB region
    float* npseudo  = nreal + NN;
    float* npseudos = npseudo + MMR;
    float* row_s    = (float*)(ws + (4 << 20));           // 4096*32 f = 512 KB
    float* pos_part = (float*)(ws + (4 << 20) + (1 << 19)); // 8192 f = 32 KB
    float* partials = pos_part + 8192;                      // 1088 f
    float* lse_pv   = partials + 1088;                      // 16 f

    prep_all<<<3840, 256, 0, stream>>>(zi, z, real, pseudo, pseudos,
        zin_bf, zn_bf, real_bf, pseudo_bf, pseudos_bf, nreal, npseudo, npseudos);

    feat_kernel<<<256 * FJS, 64, 0, stream>>>(
        zin_bf, zn_bf, y_pse, negw, w, row_s, pos_part);

    rbf_all<<<1088, 256, 0, stream>>>(real_bf, pseudo_bf, pseudos_bf,
        nreal, npseudo, npseudos, partials);

    lse_part_kernel<<<16, 256, 0, stream>>>(row_s, lse_pv);

    final_kernel<<<1, 256, 0, stream>>>(lse_pv, pos_part, partials, out);
}

// Round 5
// 129.566 us; speedup vs baseline: 1.0652x; 1.0652x over previous
//
#include <hip/hip_runtime.h>

#define NN 4096
#define DD 128
#define MMR 2048
#define KKE 1024
#define FJS 8
#define RB 16
#define JCH 128
#define NCH 4          // chunks per block: FJS*NCH*JCH == NN
#define FJS_TOT 32     // row_s partials per row = FJS * 4 waves

typedef __attribute__((ext_vector_type(8))) short s16x8;
typedef __attribute__((ext_vector_type(4))) float f32x4;
typedef unsigned short u16;
typedef unsigned int u32;

// ln(1e-45) in fp32
#define SMALLV (-103.61632918439092f)
// exp(2*v - 4) == exp2(v*K1 + K2)
#define K1EXP 2.8853900817779268f
#define K2EXP (-5.7707801635558537f)

static __device__ __forceinline__ u16 f2bf(float x) {
    u32 u = __float_as_uint(x);
    u32 r = (u + 0x7fffu + ((u >> 16) & 1u)) >> 16;
    return (u16)r;
}

static __device__ __forceinline__ f32x4 mfma_bf16(s16x8 a, s16x8 b, f32x4 c) {
    return __builtin_amdgcn_mfma_f32_16x16x32_bf16(a, b, c, 0, 0, 0);
}

static __device__ __forceinline__ void gload_lds16(const void* g, void* l) {
    __builtin_amdgcn_global_load_lds(
        (const __attribute__((address_space(1))) void*)g,
        (__attribute__((address_space(3))) void*)l, 16, 0, 0);
}

// ---------------- prep: all conversions in one launch (linear layout) ----------------
__global__ __launch_bounds__(256) void prep_all(
    const float* __restrict__ zi, const float* __restrict__ z,
    const float* __restrict__ real, const float* __restrict__ pseudo,
    const float* __restrict__ pseudos,
    u16* __restrict__ zin_bf, u16* __restrict__ zn_bf,
    u16* __restrict__ real_bf, u16* __restrict__ pseudo_bf,
    u16* __restrict__ pseudos_bf,
    float* __restrict__ nreal, float* __restrict__ npseudo,
    float* __restrict__ npseudos)
{
    int b = blockIdx.x;
    int sub = threadIdx.x >> 6, lane = threadIdx.x & 63;
    if (b < 2048) {
        int row = b * 4 + sub;   // 0..8191
        const float* src = (row < NN) ? zi : z;
        u16* dst = (row < NN) ? zin_bf : zn_bf;
        int r = (row < NN) ? row : row - NN;
        const float* p = src + (size_t)r * DD;
        float a = p[lane], c = p[lane + 64];
        float ss = a * a + c * c;
        #pragma unroll
        for (int d = 1; d < 64; d <<= 1) ss += __shfl_xor(ss, d);
        float nrm = fmaxf(sqrtf(ss), 1e-8f);
        dst[r * DD + lane]      = f2bf(a / nrm);
        dst[r * DD + lane + 64] = f2bf(c / nrm);
    } else {
        const float* src; u16* dst; float* sq; int r;
        if (b < 3072)      { r = (b - 2048) * 4 + sub; src = real;    dst = real_bf;    sq = nreal; }
        else if (b < 3584) { r = (b - 3072) * 4 + sub; src = pseudo;  dst = pseudo_bf;  sq = npseudo; }
        else               { r = (b - 3584) * 4 + sub; src = pseudos; dst = pseudos_bf; sq = npseudos; }
        const float* p = src + (size_t)r * DD;
        float a = p[lane], c = p[lane + 64];
        float ss = a * a + c * c;
        #pragma unroll
        for (int d = 1; d < 64; d <<= 1) ss += __shfl_xor(ss, d);
        if (lane == 0) sq[r] = ss;
        dst[r * DD + lane]      = f2bf(a);
        dst[r * DD + lane + 64] = f2bf(c);
    }
}

// ---------------- feature loss ----------------
// Block (4 waves) owns 16 R-rows x 512 J-cols. Per 128-col chunk, all three
// mask arrays are staged into LDS via fully-coalesced global_load_lds (each
// instr = 2 rows x 512B contiguous), double-buffered, with counted vmcnt(6)
// so a full 24KB chunk stays in flight across the barrier.
__global__ __launch_bounds__(256) void feat_kernel(
    const u16* __restrict__ zin, const u16* __restrict__ zn,
    const float* __restrict__ y_pse, const float* __restrict__ negw,
    const int* __restrict__ w,
    float* __restrict__ row_s, float* __restrict__ pos_part)
{
    __shared__ char lds[2][3][8192];   // [buf][array y/nw/w][16 rows x 512B]
    __shared__ float lds_pos[4];
    int js = blockIdx.x & (FJS - 1);
    int rb = blockIdx.x / FJS;
    int wid = threadIdx.x >> 6;
    int lane = threadIdx.x & 63;
    int lr = lane & 15, lg = lane >> 4;
    int R0 = rb * RB;
    int R = R0 + lr;
    int j00 = js * (NCH * JCH);
    const short* zin_s = (const short*)zin;
    const short* zn_s  = (const short*)zn;

    int half = lane >> 5, l32 = lane & 31;

    // B operand: zi rows R (held for whole kernel) — issued first in FIFO
    s16x8 bfrag[4];
    #pragma unroll
    for (int kk = 0; kk < 4; ++kk)
        bfrag[kk] = *(const s16x8*)(zin_s + (size_t)R * DD + kk * 32 + lg * 8);

    // stage chunk c: 6 gload_lds per wave (2 per array), each 2 rows x 512B
    #define STAGE(c) do {                                                      \
        int j_ = j00 + (c) * JCH;                                              \
        char* Lb_ = &lds[(c) & 1][0][0];                                       \
        _Pragma("unroll")                                                      \
        for (int i_ = 0; i_ < 2; ++i_) {                                       \
            int k_ = wid * 2 + i_;                                             \
            int row_ = R0 + 2 * k_ + half;                                     \
            size_t eo_ = (size_t)row_ * NN + j_ + l32 * 4;                     \
            gload_lds16(y_pse + eo_, Lb_ + k_ * 1024);                         \
            gload_lds16(negw  + eo_, Lb_ + 8192 + k_ * 1024);                  \
            gload_lds16(w     + eo_, Lb_ + 16384 + k_ * 1024);                 \
        }                                                                      \
    } while (0)

    STAGE(0);

    float s0 = 0.0f, pos = 0.0f;

    #pragma unroll
    for (int c = 0; c < NCH; ++c) {
        // A-frags for this chunk (2 tiles x 2 arrays x 4 K-frags) — in FIFO
        // ahead of the next stage.
        s16x8 an[2][4], ai[2][4];
        #pragma unroll
        for (int t = 0; t < 2; ++t) {
            int jr = j00 + c * JCH + wid * 32 + t * 16 + lr;
            #pragma unroll
            for (int kk = 0; kk < 4; ++kk) {
                an[t][kk] = *(const s16x8*)(zn_s  + (size_t)jr * DD + kk * 32 + lg * 8);
                ai[t][kk] = *(const s16x8*)(zin_s + (size_t)jr * DD + kk * 32 + lg * 8);
            }
        }
        if (c + 1 < NCH) {
            STAGE(c + 1);
            // FIFO: [stage(c):6][afrag(c):16][stage(c+1):6] -> keep 6
            asm volatile("s_waitcnt vmcnt(6)" ::: "memory");
        } else {
            asm volatile("s_waitcnt vmcnt(0)" ::: "memory");
        }
        __builtin_amdgcn_s_barrier();

        const char* Lb = &lds[c & 1][0][0];
        #pragma unroll
        for (int t = 0; t < 2; ++t) {
            f32x4 accc = {0.f, 0.f, 0.f, 0.f}, acci = {0.f, 0.f, 0.f, 0.f};
            #pragma unroll
            for (int kk = 0; kk < 4; ++kk) {
                accc = mfma_bf16(an[t][kk], bfrag[kk], accc);   // C[J,R]=z[J]·zi[R]
                acci = mfma_bf16(ai[t][kk], bfrag[kk], acci);   // C[J,R]=zi[J]·zi[R]
            }
            int mo = lr * 512 + (wid * 32 + t * 16 + lg * 4) * 4;
            float4 y4 = *(const float4*)(Lb + mo);
            float4 n4 = *(const float4*)(Lb + 8192 + mo);
            int4   w4 = *(const int4*)(Lb + 16384 + mo);
            int j0 = j00 + c * JCH + wid * 32 + t * 16;
            float ya[4] = {y4.x, y4.y, y4.z, y4.w};
            float na[4] = {n4.x, n4.y, n4.z, n4.w};
            int   wa[4] = {w4.x, w4.y, w4.z, w4.w};
            #pragma unroll
            for (int r = 0; r < 4; ++r) {
                int J = j0 + lg * 4 + r;
                float y = ya[r];
                bool wm = (wa[r] != 0) || (R == J);
                float cross = accc[r] * 2.0f;   // cos / TEMP
                float inter = acci[r] * 2.0f;
                if (wm && (y > 0.0f)) pos += y * cross;
                bool nm = (!wm) && (y == 0.0f);
                float nwc = fmaxf(na[r], 0.0f);
                float vc = nm ? nwc * cross : 0.0f;
                vc = (vc == 0.0f) ? SMALLV : vc;
                float vi = nm ? nwc * inter : 0.0f;
                vi = (vi == 0.0f) ? SMALLV : vi;
                s0 += exp2f(fmaf(vc, K1EXP, K2EXP)) + exp2f(fmaf(vi, K1EXP, K2EXP));
            }
        }
        asm volatile("s_waitcnt lgkmcnt(0)" ::: "memory");
        __builtin_amdgcn_s_barrier();
    }

    // s0: lanes lr, lr+16, lr+32, lr+48 share row R; combine over lg
    #pragma unroll
    for (int d = 16; d < 64; d <<= 1) s0 += __shfl_xor(s0, d);
    if (lg == 0) row_s[(size_t)R * FJS_TOT + js * 4 + wid] = s0;
    #pragma unroll
    for (int d = 1; d < 64; d <<= 1) pos += __shfl_xor(pos, d);
    if (lane == 0) lds_pos[wid] = pos;
    __syncthreads();
    if (threadIdx.x == 0)
        pos_part[blockIdx.x] = lds_pos[0] + lds_pos[1] + lds_pos[2] + lds_pos[3];
    #undef STAGE
}

// ---------------- RBF pair-sums, all four in one launch ----------------
__global__ __launch_bounds__(256) void rbf_all(
    const u16* __restrict__ real_bf, const u16* __restrict__ pseudo_bf,
    const u16* __restrict__ pseudos_bf,
    const float* __restrict__ nreal, const float* __restrict__ npseudo,
    const float* __restrict__ npseudos,
    float* __restrict__ partials)
{
    int b = blockIdx.x;
    const u16 *X, *Y; const float *nx, *ny;
    int js, cols, same, local;
    if (b < 512)       { X = real_bf;    Y = real_bf;    nx = nreal;    ny = nreal;    js = 16; cols = 256; same = 1; local = b; }
    else if (b < 768)  { X = pseudo_bf;  Y = pseudo_bf;  nx = npseudo;  ny = npseudo;  js = 16; cols = 128; same = 1; local = b - 512; }
    else if (b < 1024) { X = real_bf;    Y = pseudo_bf;  nx = nreal;    ny = npseudo;  js = 8;  cols = 256; same = 0; local = b - 768; }
    else               { X = pseudos_bf; Y = pseudos_bf; nx = npseudos; ny = npseudos; js = 8;  cols = 128; same = 1; local = b - 1024; }
    int jsx = local % js;
    int rb  = local / js;
    int wid = threadIdx.x >> 6;
    int lane = threadIdx.x & 63;
    int lr = lane & 15, lg = lane >> 4;
    int row0 = rb * 128 + wid * 32;
    const short* Xs = (const short*)X;
    const short* Ys = (const short*)Y;
    s16x8 a0[4], a1[4];
    #pragma unroll
    for (int kk = 0; kk < 4; ++kk) {
        a0[kk] = *(const s16x8*)(Xs + (size_t)(row0 + lr) * DD + kk * 32 + lg * 8);
        a1[kk] = *(const s16x8*)(Xs + (size_t)(row0 + 16 + lr) * DD + kk * 32 + lg * 8);
    }
    float nx0[4], nx1[4];
    #pragma unroll
    for (int r = 0; r < 4; ++r) {
        nx0[r] = nx[row0 + lg * 4 + r];
        nx1[r] = nx[row0 + 16 + lg * 4 + r];
    }
    float sum = 0.0f;
    int j0base = jsx * cols;
    for (int j0 = j0base; j0 < j0base + cols; j0 += 16) {
        int brow = j0 + lr;
        f32x4 c0 = {0.f, 0.f, 0.f, 0.f}, c1 = {0.f, 0.f, 0.f, 0.f};
        #pragma unroll
        for (int kk = 0; kk < 4; ++kk) {
            s16x8 bb = *(const s16x8*)(Ys + (size_t)brow * DD + kk * 32 + lg * 8);
            c0 = mfma_bf16(a0[kk], bb, c0);
            c1 = mfma_bf16(a1[kk], bb, c1);
        }
        int J = j0 + lr;
        float nyJ = ny[J];
        #pragma unroll
        for (int r = 0; r < 4; ++r) {
            int R0 = row0 + lg * 4 + r;
            float d0 = fmaxf(nx0[r] + nyJ - 2.0f * c0[r], 0.0f);
            if (!(same && (R0 == J))) sum += __expf(-d0 * 0.125f);
            int R1 = R0 + 16;
            float d1 = fmaxf(nx1[r] + nyJ - 2.0f * c1[r], 0.0f);
            if (!(same && (R1 == J))) sum += __expf(-d1 * 0.125f);
        }
    }
    #pragma unroll
    for (int d = 1; d < 64; d <<= 1) sum += __shfl_xor(sum, d);
    __shared__ float lds_s[4];
    if (lane == 0) lds_s[wid] = sum;
    __syncthreads();
    if (threadIdx.x == 0)
        partials[b] = lds_s[0] + lds_s[1] + lds_s[2] + lds_s[3];
}

// ---------------- per-row LSE finish ----------------
__global__ __launch_bounds__(256) void lse_part_kernel(
    const float* __restrict__ row_s, float* __restrict__ lse_part)
{
    int R = blockIdx.x * 256 + threadIdx.x;
    float s = 0.0f;
    #pragma unroll
    for (int k = 0; k < FJS_TOT; ++k) s += row_s[(size_t)R * FJS_TOT + k];
    float v = 4.0f + __logf(s);   // fixed-max LSE: max = 4
    #pragma unroll
    for (int d = 1; d < 64; d <<= 1) v += __shfl_xor(v, d);
    __shared__ float l[4];
    if ((threadIdx.x & 63) == 0) l[threadIdx.x >> 6] = v;
    __syncthreads();
    if (threadIdx.x == 0) lse_part[blockIdx.x] = l[0] + l[1] + l[2] + l[3];
}

// ---------------- final (1 block, deterministic) ----------------
__global__ __launch_bounds__(256) void final_kernel(
    const float* __restrict__ lse_part, const float* __restrict__ pos_part,
    const float* __restrict__ partials, float* __restrict__ out)
{
    int t = threadIdx.x;
    float lse = (t < 16) ? lse_part[t] : 0.0f;
    float pos = 0.0f;
    #pragma unroll
    for (int i = 0; i < 8; ++i) pos += pos_part[t + 256 * i];
    float xx = partials[t] + partials[t + 256];
    float yy = partials[512 + t];
    float xy = partials[768 + t];
    float pp = (t < 64) ? partials[1024 + t] : 0.0f;
    __shared__ float red[256];
    float vals[6] = {lse, pos, xx, yy, xy, pp};
    float tot[6];
    #pragma unroll
    for (int v = 0; v < 6; ++v) {
        red[t] = vals[v];
        __syncthreads();
        for (int d = 128; d > 0; d >>= 1) {
            if (t < d) red[t] += red[t + d];
            __syncthreads();
        }
        tot[v] = red[0];
        __syncthreads();
    }
    if (t == 0) {
        float feat = (tot[0] - tot[1]) / (float)NN;
        float sxx = tot[2] / ((float)NN * (NN - 1));
        float syy = tot[3] / ((float)MMR * (MMR - 1));
        float sxy = 2.0f * tot[4] / ((float)NN * MMR);
        out[0] = feat + sxx + syy - sxy + tot[5];
    }
}

extern "C" void kernel_launch(void* const* d_in, const int* in_sizes, int n_in,
                              void* d_out, int out_size, void* d_ws, size_t ws_size,
                              hipStream_t stream) {
    const float* zi      = (const float*)d_in[0];
    const float* z       = (const float*)d_in[1];
    const float* y_pse   = (const float*)d_in[2];
    const float* negw    = (const float*)d_in[3];
    const float* real    = (const float*)d_in[4];
    const float* pseudo  = (const float*)d_in[5];
    const float* pseudos = (const float*)d_in[6];
    const int*   w       = (const int*)d_in[7];
    float* out = (float*)d_out;

    char* ws = (char*)d_ws;
    u16* zin_bf     = (u16*)(ws + 0);                     // 1 MB
    u16* zn_bf      = (u16*)(ws + (1 << 20));             // 1 MB
    u16* real_bf    = (u16*)(ws + (2 << 20));             // 1 MB
    u16* pseudo_bf  = (u16*)(ws + (3 << 20));             // 512 KB
    u16* pseudos_bf = (u16*)(ws + (3 << 20) + (1 << 19)); // 256 KB
    float* nreal    = (float*)(ws + (15 << 18));          // 16 KB region
    float* npseudo  = nreal + NN;
    float* npseudos = npseudo + MMR;
    float* row_s    = (float*)(ws + (4 << 20));           // 4096*32 f = 512 KB
    float* pos_part = (float*)(ws + (4 << 20) + (1 << 19)); // 2048 f
    float* partials = pos_part + 2048;                      // 1088 f
    float* lse_pv   = partials + 1088;                      // 16 f

    prep_all<<<3840, 256, 0, stream>>>(zi, z, real, pseudo, pseudos,
        zin_bf, zn_bf, real_bf, pseudo_bf, pseudos_bf, nreal, npseudo, npseudos);

    feat_kernel<<<(NN / RB) * FJS, 256, 0, stream>>>(
        zin_bf, zn_bf, y_pse, negw, w, row_s, pos_part);

    rbf_all<<<1088, 256, 0, stream>>>(real_bf, pseudo_bf, pseudos_bf,
        nreal, npseudo, npseudos, partials);

    lse_part_kernel<<<16, 256, 0, stream>>>(row_s, lse_pv);

    final_kernel<<<1, 256, 0, stream>>>(lse_pv, pos_part, partials, out);
}